// Round 5
// baseline (1063.814 us; speedup 1.0000x reference)
//
#include <hip/hip_runtime.h>

#define NTH 256
#define N_NODES 2048

// Symmetrized coefficient table (floats):
//   l3: [0 .. 165*12)   record t: [ b30 s0..2 | b31 s0p0..s2p2 ]   stride 48B (16B-aligned)
//   l2: [1980 .. +45*8) record t: [ b20 s0..1 | b21 s0p0..s1p2 ]   stride 32B
//   l1: [2340 .. +9*4)  record a: [ b10 | b11 p0..2 ]              stride 16B
#define L2_OFF (165 * 12)            // 1980
#define L1_OFF (L2_OFF + 45 * 8)     // 2340
#define TAB_FLOATS (L1_OFF + 9 * 4)  // 2376

__global__ void mace_build_tables(
    const float* __restrict__ b10, const float* __restrict__ b11,
    const float* __restrict__ b20, const float* __restrict__ b21,
    const float* __restrict__ b30, const float* __restrict__ b31,
    float* __restrict__ tab)
{
    const int t = threadIdx.x;
    if (t < 165) {
        // closed-form decode: rank -> (i<=j<=k) over 9
        int r = t, i = 0;
        while (r >= (9 - i) * (10 - i) / 2) { r -= (9 - i) * (10 - i) / 2; i++; }
        int j = i;
        while (r >= 9 - j) { r -= 9 - j; j++; }
        int k = j + r;

        float s[12];
        #pragma unroll
        for (int q = 0; q < 12; q++) s[q] = 0.f;
        auto add3 = [&](int a, int b, int c2) {
            int o30 = ((a * 9 + b) * 9 + c2) * 3;   // b30: (9,9,9,3,1)
            int o31 = o30 * 3;                      // b31: (9,9,9,3,3)
            #pragma unroll
            for (int q = 0; q < 3; q++) s[q] += b30[o30 + q];
            #pragma unroll
            for (int q = 0; q < 9; q++) s[3 + q] += b31[o31 + q];
        };
        if (i == j && j == k) { add3(i, j, k); }
        else if (i == j)      { add3(i, i, k); add3(i, k, i); add3(k, i, i); }
        else if (j == k)      { add3(i, j, j); add3(j, i, j); add3(j, j, i); }
        else { add3(i,j,k); add3(i,k,j); add3(j,i,k); add3(j,k,i); add3(k,i,j); add3(k,j,i); }
        #pragma unroll
        for (int q = 0; q < 12; q++) tab[t * 12 + q] = s[q];
    } else if (t < 210) {
        int u = t - 165;
        int r = u, i = 0;
        while (r >= 9 - i) { r -= 9 - i; i++; }
        int j = i + r;

        float s[8];
        #pragma unroll
        for (int q = 0; q < 8; q++) s[q] = 0.f;
        auto add2 = [&](int a, int b) {
            int o20 = (a * 9 + b) * 2;   // b20: (9,9,2,1)
            int o21 = o20 * 3;           // b21: (9,9,2,3)
            #pragma unroll
            for (int q = 0; q < 2; q++) s[q] += b20[o20 + q];
            #pragma unroll
            for (int q = 0; q < 6; q++) s[2 + q] += b21[o21 + q];
        };
        if (i == j) add2(i, i); else { add2(i, j); add2(j, i); }
        #pragma unroll
        for (int q = 0; q < 8; q++) tab[L2_OFF + u * 8 + q] = s[q];
    } else if (t < 219) {
        int a = t - 210;
        tab[L1_OFF + a * 4 + 0] = b10[a];                 // b10: (9,1,1)
        #pragma unroll
        for (int p = 0; p < 3; p++) tab[L1_OFF + a * 4 + 1 + p] = b11[a * 3 + p];  // b11: (9,1,3)
    }
}

// RPT=2: each thread handles rows (mb, mb+64) of one node; wave = one node
// (z, node wave-uniform). Coefficients read from LDS with uniform-address
// broadcast ds_read_b128 (in-order -> fine-grained lgkmcnt pipelining; SMEM
// s_loads are out-of-order and forced lgkmcnt(0) drains -> R4's 24% VALUBusy).
__global__ __launch_bounds__(NTH, 2) void mace_main(
    const float* __restrict__ nf, const int* __restrict__ spec,
    const float* __restrict__ tab,
    const float* __restrict__ w10, const float* __restrict__ w11,
    const float* __restrict__ w20, const float* __restrict__ w21,
    const float* __restrict__ w30, const float* __restrict__ w31,
    float* __restrict__ out)
{
    __shared__ __align__(16) float lt[TAB_FLOATS];
    #pragma unroll
    for (int idx = threadIdx.x; idx < TAB_FLOATS; idx += NTH)
        lt[idx] = tab[idx];
    __syncthreads();

    const int g    = blockIdx.x * NTH + threadIdx.x;   // 131072 threads
    const int node = g >> 6;                           // 64 threads per node
    const int mb   = g & 63;                           // rows mb, mb+64

    const float* nfp = nf + node * 1152;
    float f[2][9];
    #pragma unroll
    for (int r = 0; r < 2; r++) {
        const int m = mb + 64 * r;
        f[r][0] = nfp[m];                                          // 0e
        #pragma unroll
        for (int j = 0; j < 3; j++) f[r][1 + j] = nfp[128 + m * 3 + j];  // 1o
        #pragma unroll
        for (int j = 0; j < 5; j++) f[r][4 + j] = nfp[512 + m * 5 + j];  // 2e
    }

    const int z = spec[node];   // wave-uniform

    float w30v[2][3], w31v[2][3], w20v[2][2], w21v[2][2], w10v[2], w11v[2];
    #pragma unroll
    for (int r = 0; r < 2; r++) {
        const int m = mb + 64 * r;
        #pragma unroll
        for (int s = 0; s < 3; s++) {
            w30v[r][s] = w30[(z * 3 + s) * 128 + m];
            w31v[r][s] = w31[(z * 3 + s) * 128 + m];
        }
        #pragma unroll
        for (int s = 0; s < 2; s++) {
            w20v[r][s] = w20[(z * 2 + s) * 128 + m];
            w21v[r][s] = w21[(z * 2 + s) * 128 + m];
        }
        w10v[r] = w10[z * 128 + m];
        w11v[r] = w11[z * 128 + m];
    }

    float acc[2][4];
    #pragma unroll
    for (int r = 0; r < 2; r++)
        #pragma unroll
        for (int p = 0; p < 4; p++) acc[r][p] = 0.f;

    // ---- nu = 3 : 165 symmetric monomials ----
    {
        float t3[2][12];
        #pragma unroll
        for (int r = 0; r < 2; r++)
            #pragma unroll
            for (int q = 0; q < 12; q++) t3[r][q] = 0.f;

        int t = 0;
        #pragma unroll
        for (int i = 0; i < 9; i++) {
            #pragma unroll
            for (int j = i; j < 9; j++) {
                const float fij0 = f[0][i] * f[0][j];
                const float fij1 = f[1][i] * f[1][j];
                #pragma unroll
                for (int k = j; k < 9; k++) {
                    const float4* c4 = (const float4*)&lt[t * 12];
                    float cc[12];
                    *(float4*)&cc[0] = c4[0];
                    *(float4*)&cc[4] = c4[1];
                    *(float4*)&cc[8] = c4[2];
                    const float m0 = fij0 * f[0][k];
                    const float m1 = fij1 * f[1][k];
                    #pragma unroll
                    for (int q = 0; q < 12; q++) {
                        t3[0][q] = fmaf(cc[q], m0, t3[0][q]);
                        t3[1][q] = fmaf(cc[q], m1, t3[1][q]);
                    }
                    t++;
                }
            }
        }
        #pragma unroll
        for (int r = 0; r < 2; r++)
            #pragma unroll
            for (int s = 0; s < 3; s++) {
                acc[r][0] = fmaf(w30v[r][s], t3[r][s], acc[r][0]);
                #pragma unroll
                for (int p = 0; p < 3; p++)
                    acc[r][1 + p] = fmaf(w31v[r][s], t3[r][3 + s * 3 + p], acc[r][1 + p]);
            }
    }

    // ---- nu = 2 : 45 monomials ----
    {
        float t2[2][8];
        #pragma unroll
        for (int r = 0; r < 2; r++)
            #pragma unroll
            for (int q = 0; q < 8; q++) t2[r][q] = 0.f;

        int t = 0;
        #pragma unroll
        for (int i = 0; i < 9; i++) {
            #pragma unroll
            for (int j = i; j < 9; j++) {
                const float4* c4 = (const float4*)&lt[L2_OFF + t * 8];
                float cc[8];
                *(float4*)&cc[0] = c4[0];
                *(float4*)&cc[4] = c4[1];
                const float m0 = f[0][i] * f[0][j];
                const float m1 = f[1][i] * f[1][j];
                #pragma unroll
                for (int q = 0; q < 8; q++) {
                    t2[0][q] = fmaf(cc[q], m0, t2[0][q]);
                    t2[1][q] = fmaf(cc[q], m1, t2[1][q]);
                }
                t++;
            }
        }
        #pragma unroll
        for (int r = 0; r < 2; r++)
            #pragma unroll
            for (int s = 0; s < 2; s++) {
                acc[r][0] = fmaf(w20v[r][s], t2[r][s], acc[r][0]);
                #pragma unroll
                for (int p = 0; p < 3; p++)
                    acc[r][1 + p] = fmaf(w21v[r][s], t2[r][2 + s * 3 + p], acc[r][1 + p]);
            }
    }

    // ---- nu = 1 : 9 terms ----
    {
        float t1[2][4];
        #pragma unroll
        for (int r = 0; r < 2; r++)
            #pragma unroll
            for (int q = 0; q < 4; q++) t1[r][q] = 0.f;

        #pragma unroll
        for (int a = 0; a < 9; a++) {
            const float4 cv = *(const float4*)&lt[L1_OFF + a * 4];
            const float cc[4] = {cv.x, cv.y, cv.z, cv.w};
            #pragma unroll
            for (int q = 0; q < 4; q++) {
                t1[0][q] = fmaf(cc[q], f[0][a], t1[0][q]);
                t1[1][q] = fmaf(cc[q], f[1][a], t1[1][q]);
            }
        }
        #pragma unroll
        for (int r = 0; r < 2; r++) {
            acc[r][0] = fmaf(w10v[r], t1[r][0], acc[r][0]);
            #pragma unroll
            for (int p = 0; p < 3; p++)
                acc[r][1 + p] = fmaf(w11v[r], t1[r][1 + p], acc[r][1 + p]);
        }
    }

    // ---- store: out (n, 512) = [ (n,128) p=0 | (n,128,3) p=1..3 ] ----
    float* op = out + node * 512;
    #pragma unroll
    for (int r = 0; r < 2; r++) {
        const int m = mb + 64 * r;
        op[m] = acc[r][0];
        #pragma unroll
        for (int p = 0; p < 3; p++) op[128 + m * 3 + p] = acc[r][1 + p];
    }
}

extern "C" void kernel_launch(void* const* d_in, const int* in_sizes, int n_in,
                              void* d_out, int out_size, void* d_ws, size_t ws_size,
                              hipStream_t stream) {
    // setup_inputs() dict order is INTERLEAVED: node_feats, species,
    // b10, w10, b11, w11, b20, w20, b21, w21, b30, w30, b31, w31
    const float* nf  = (const float*)d_in[0];
    const int* spec  = (const int*)d_in[1];
    const float* b10 = (const float*)d_in[2];
    const float* w10 = (const float*)d_in[3];
    const float* b11 = (const float*)d_in[4];
    const float* w11 = (const float*)d_in[5];
    const float* b20 = (const float*)d_in[6];
    const float* w20 = (const float*)d_in[7];
    const float* b21 = (const float*)d_in[8];
    const float* w21 = (const float*)d_in[9];
    const float* b30 = (const float*)d_in[10];
    const float* w30 = (const float*)d_in[11];
    const float* b31 = (const float*)d_in[12];
    const float* w31 = (const float*)d_in[13];
    float* out = (float*)d_out;
    float* tab = (float*)d_ws;   // 2376 floats

    mace_build_tables<<<1, NTH, 0, stream>>>(b10, b11, b20, b21, b30, b31, tab);

    const int grid = (N_NODES * 64) / NTH;   // 512 blocks (RPT=2)
    mace_main<<<grid, NTH, 0, stream>>>(
        nf, spec, tab, w10, w11, w20, w21, w30, w31, out);
}

// Round 6
// 446.721 us; speedup vs baseline: 2.3814x; 2.3814x over previous
//
#include <hip/hip_runtime.h>

#define NTH 256
#define N_NODES 2048

// Symmetrized coefficient table (floats):
//   l3: [0 .. 165*12)   record t: [ b30 s0..2 | b31 s0p0..s2p2 ]   stride 48B (16B-aligned)
//   l2: [1980 .. +45*8) record t: [ b20 s0..1 | b21 s0p0..s1p2 ]   stride 32B
//   l1: [2340 .. +9*4)  record a: [ b10 | b11 p0..2 ]              stride 16B
#define L2_OFF (165 * 12)            // 1980
#define L1_OFF (L2_OFF + 45 * 8)     // 2340
#define TAB_FLOATS (L1_OFF + 9 * 4)  // 2376

__global__ void mace_build_tables(
    const float* __restrict__ b10, const float* __restrict__ b11,
    const float* __restrict__ b20, const float* __restrict__ b21,
    const float* __restrict__ b30, const float* __restrict__ b31,
    float* __restrict__ tab)
{
    const int t = threadIdx.x;
    if (t < 165) {
        // closed-form decode: rank -> (i<=j<=k) over 9
        int r = t, i = 0;
        while (r >= (9 - i) * (10 - i) / 2) { r -= (9 - i) * (10 - i) / 2; i++; }
        int j = i;
        while (r >= 9 - j) { r -= 9 - j; j++; }
        int k = j + r;

        float s[12];
        #pragma unroll
        for (int q = 0; q < 12; q++) s[q] = 0.f;
        auto add3 = [&](int a, int b, int c2) {
            int o30 = ((a * 9 + b) * 9 + c2) * 3;   // b30: (9,9,9,3,1)
            int o31 = o30 * 3;                      // b31: (9,9,9,3,3)
            #pragma unroll
            for (int q = 0; q < 3; q++) s[q] += b30[o30 + q];
            #pragma unroll
            for (int q = 0; q < 9; q++) s[3 + q] += b31[o31 + q];
        };
        if (i == j && j == k) { add3(i, j, k); }
        else if (i == j)      { add3(i, i, k); add3(i, k, i); add3(k, i, i); }
        else if (j == k)      { add3(i, j, j); add3(j, i, j); add3(j, j, i); }
        else { add3(i,j,k); add3(i,k,j); add3(j,i,k); add3(j,k,i); add3(k,i,j); add3(k,j,i); }
        #pragma unroll
        for (int q = 0; q < 12; q++) tab[t * 12 + q] = s[q];
    } else if (t < 210) {
        int u = t - 165;
        int r = u, i = 0;
        while (r >= 9 - i) { r -= 9 - i; i++; }
        int j = i + r;

        float s[8];
        #pragma unroll
        for (int q = 0; q < 8; q++) s[q] = 0.f;
        auto add2 = [&](int a, int b) {
            int o20 = (a * 9 + b) * 2;   // b20: (9,9,2,1)
            int o21 = o20 * 3;           // b21: (9,9,2,3)
            #pragma unroll
            for (int q = 0; q < 2; q++) s[q] += b20[o20 + q];
            #pragma unroll
            for (int q = 0; q < 6; q++) s[2 + q] += b21[o21 + q];
        };
        if (i == j) add2(i, i); else { add2(i, j); add2(j, i); }
        #pragma unroll
        for (int q = 0; q < 8; q++) tab[L2_OFF + u * 8 + q] = s[q];
    } else if (t < 219) {
        int a = t - 210;
        tab[L1_OFF + a * 4 + 0] = b10[a];                 // b10: (9,1,1)
        #pragma unroll
        for (int p = 0; p < 3; p++) tab[L1_OFF + a * 4 + 1 + p] = b11[a * 3 + p];  // b11: (9,1,3)
    }
}

// 12 fused FMAs into accumulator array T (compile-time indices only) from
// three float4 VALUES (never written through pointers -> stays in VGPRs;
// R5's punned local arrays went to scratch: 2.5 GB spill traffic).
#define FMA12(T, mm) do { \
    T[0]  = fmaf(c0.x, (mm), T[0]);  T[1]  = fmaf(c0.y, (mm), T[1]);  \
    T[2]  = fmaf(c0.z, (mm), T[2]);  T[3]  = fmaf(c0.w, (mm), T[3]);  \
    T[4]  = fmaf(c1.x, (mm), T[4]);  T[5]  = fmaf(c1.y, (mm), T[5]);  \
    T[6]  = fmaf(c1.z, (mm), T[6]);  T[7]  = fmaf(c1.w, (mm), T[7]);  \
    T[8]  = fmaf(c2.x, (mm), T[8]);  T[9]  = fmaf(c2.y, (mm), T[9]);  \
    T[10] = fmaf(c2.z, (mm), T[10]); T[11] = fmaf(c2.w, (mm), T[11]); } while (0)

#define FMA8(T, mm) do { \
    T[0] = fmaf(c0.x, (mm), T[0]); T[1] = fmaf(c0.y, (mm), T[1]); \
    T[2] = fmaf(c0.z, (mm), T[2]); T[3] = fmaf(c0.w, (mm), T[3]); \
    T[4] = fmaf(c1.x, (mm), T[4]); T[5] = fmaf(c1.y, (mm), T[5]); \
    T[6] = fmaf(c1.z, (mm), T[6]); T[7] = fmaf(c1.w, (mm), T[7]); } while (0)

// RPT=2: thread handles rows (mb, mb+64) of one node; wave = one node.
// Coefficients: uniform-address broadcast ds_read_b128 from LDS (in-order,
// pipelinable lgkmcnt; R4's SMEM s_loads forced full drains -> 24% VALUBusy).
__global__ __launch_bounds__(NTH, 2) void mace_main(
    const float* __restrict__ nf, const int* __restrict__ spec,
    const float* __restrict__ tab,
    const float* __restrict__ w10, const float* __restrict__ w11,
    const float* __restrict__ w20, const float* __restrict__ w21,
    const float* __restrict__ w30, const float* __restrict__ w31,
    float* __restrict__ out)
{
    __shared__ __align__(16) float lt[TAB_FLOATS];
    for (int idx = threadIdx.x; idx < TAB_FLOATS; idx += NTH)
        lt[idx] = tab[idx];
    __syncthreads();

    const int g    = blockIdx.x * NTH + threadIdx.x;   // 131072 threads
    const int node = g >> 6;                           // 64 threads per node
    const int mb   = g & 63;                           // rows mb, mb+64

    const float* nfp = nf + node * 1152;
    float f0[9], f1[9];
    {
        const int m0i = mb, m1i = mb + 64;
        f0[0] = nfp[m0i];
        f1[0] = nfp[m1i];
        #pragma unroll
        for (int j = 0; j < 3; j++) { f0[1 + j] = nfp[128 + m0i * 3 + j]; f1[1 + j] = nfp[128 + m1i * 3 + j]; }
        #pragma unroll
        for (int j = 0; j < 5; j++) { f0[4 + j] = nfp[512 + m0i * 5 + j]; f1[4 + j] = nfp[512 + m1i * 5 + j]; }
    }

    const int z = spec[node];   // wave-uniform

    float w30v[2][3], w31v[2][3], w20v[2][2], w21v[2][2], w10v[2], w11v[2];
    #pragma unroll
    for (int r = 0; r < 2; r++) {
        const int m = mb + 64 * r;
        #pragma unroll
        for (int s = 0; s < 3; s++) {
            w30v[r][s] = w30[(z * 3 + s) * 128 + m];
            w31v[r][s] = w31[(z * 3 + s) * 128 + m];
        }
        #pragma unroll
        for (int s = 0; s < 2; s++) {
            w20v[r][s] = w20[(z * 2 + s) * 128 + m];
            w21v[r][s] = w21[(z * 2 + s) * 128 + m];
        }
        w10v[r] = w10[z * 128 + m];
        w11v[r] = w11[z * 128 + m];
    }

    float acc0[4] = {0.f, 0.f, 0.f, 0.f};
    float acc1[4] = {0.f, 0.f, 0.f, 0.f};

    // ---- nu = 3 : 165 symmetric monomials, fully unrolled ----
    {
        float t3a[12], t3b[12];
        #pragma unroll
        for (int q = 0; q < 12; q++) { t3a[q] = 0.f; t3b[q] = 0.f; }

        int t = 0;
        #pragma unroll
        for (int i = 0; i < 9; i++) {
            #pragma unroll
            for (int j = i; j < 9; j++) {
                const float fij0 = f0[i] * f0[j];
                const float fij1 = f1[i] * f1[j];
                #pragma unroll
                for (int k = j; k < 9; k++) {
                    const float4 c0 = *(const float4*)(lt + t * 12);
                    const float4 c1 = *(const float4*)(lt + t * 12 + 4);
                    const float4 c2 = *(const float4*)(lt + t * 12 + 8);
                    const float m0 = fij0 * f0[k];
                    const float m1 = fij1 * f1[k];
                    FMA12(t3a, m0);
                    FMA12(t3b, m1);
                    t++;
                }
            }
        }
        #pragma unroll
        for (int s = 0; s < 3; s++) {
            acc0[0] = fmaf(w30v[0][s], t3a[s], acc0[0]);
            acc1[0] = fmaf(w30v[1][s], t3b[s], acc1[0]);
            #pragma unroll
            for (int p = 0; p < 3; p++) {
                acc0[1 + p] = fmaf(w31v[0][s], t3a[3 + s * 3 + p], acc0[1 + p]);
                acc1[1 + p] = fmaf(w31v[1][s], t3b[3 + s * 3 + p], acc1[1 + p]);
            }
        }
    }

    // ---- nu = 2 : 45 monomials ----
    {
        float t2a[8], t2b[8];
        #pragma unroll
        for (int q = 0; q < 8; q++) { t2a[q] = 0.f; t2b[q] = 0.f; }

        int t = 0;
        #pragma unroll
        for (int i = 0; i < 9; i++) {
            #pragma unroll
            for (int j = i; j < 9; j++) {
                const float4 c0 = *(const float4*)(lt + L2_OFF + t * 8);
                const float4 c1 = *(const float4*)(lt + L2_OFF + t * 8 + 4);
                const float m0 = f0[i] * f0[j];
                const float m1 = f1[i] * f1[j];
                FMA8(t2a, m0);
                FMA8(t2b, m1);
                t++;
            }
        }
        #pragma unroll
        for (int s = 0; s < 2; s++) {
            acc0[0] = fmaf(w20v[0][s], t2a[s], acc0[0]);
            acc1[0] = fmaf(w20v[1][s], t2b[s], acc1[0]);
            #pragma unroll
            for (int p = 0; p < 3; p++) {
                acc0[1 + p] = fmaf(w21v[0][s], t2a[2 + s * 3 + p], acc0[1 + p]);
                acc1[1 + p] = fmaf(w21v[1][s], t2b[2 + s * 3 + p], acc1[1 + p]);
            }
        }
    }

    // ---- nu = 1 : 9 terms ----
    {
        float t1a[4] = {0.f, 0.f, 0.f, 0.f};
        float t1b[4] = {0.f, 0.f, 0.f, 0.f};
        #pragma unroll
        for (int a = 0; a < 9; a++) {
            const float4 cv = *(const float4*)(lt + L1_OFF + a * 4);
            t1a[0] = fmaf(cv.x, f0[a], t1a[0]); t1b[0] = fmaf(cv.x, f1[a], t1b[0]);
            t1a[1] = fmaf(cv.y, f0[a], t1a[1]); t1b[1] = fmaf(cv.y, f1[a], t1b[1]);
            t1a[2] = fmaf(cv.z, f0[a], t1a[2]); t1b[2] = fmaf(cv.z, f1[a], t1b[2]);
            t1a[3] = fmaf(cv.w, f0[a], t1a[3]); t1b[3] = fmaf(cv.w, f1[a], t1b[3]);
        }
        acc0[0] = fmaf(w10v[0], t1a[0], acc0[0]);
        acc1[0] = fmaf(w10v[1], t1b[0], acc1[0]);
        #pragma unroll
        for (int p = 0; p < 3; p++) {
            acc0[1 + p] = fmaf(w11v[0], t1a[1 + p], acc0[1 + p]);
            acc1[1 + p] = fmaf(w11v[1], t1b[1 + p], acc1[1 + p]);
        }
    }

    // ---- store: out (n, 512) = [ (n,128) p=0 | (n,128,3) p=1..3 ] ----
    float* op = out + node * 512;
    {
        const int m0i = mb, m1i = mb + 64;
        op[m0i] = acc0[0];
        op[m1i] = acc1[0];
        #pragma unroll
        for (int p = 0; p < 3; p++) {
            op[128 + m0i * 3 + p] = acc0[1 + p];
            op[128 + m1i * 3 + p] = acc1[1 + p];
        }
    }
}

extern "C" void kernel_launch(void* const* d_in, const int* in_sizes, int n_in,
                              void* d_out, int out_size, void* d_ws, size_t ws_size,
                              hipStream_t stream) {
    // setup_inputs() dict order is INTERLEAVED: node_feats, species,
    // b10, w10, b11, w11, b20, w20, b21, w21, b30, w30, b31, w31
    const float* nf  = (const float*)d_in[0];
    const int* spec  = (const int*)d_in[1];
    const float* b10 = (const float*)d_in[2];
    const float* w10 = (const float*)d_in[3];
    const float* b11 = (const float*)d_in[4];
    const float* w11 = (const float*)d_in[5];
    const float* b20 = (const float*)d_in[6];
    const float* w20 = (const float*)d_in[7];
    const float* b21 = (const float*)d_in[8];
    const float* w21 = (const float*)d_in[9];
    const float* b30 = (const float*)d_in[10];
    const float* w30 = (const float*)d_in[11];
    const float* b31 = (const float*)d_in[12];
    const float* w31 = (const float*)d_in[13];
    float* out = (float*)d_out;
    float* tab = (float*)d_ws;   // 2376 floats

    mace_build_tables<<<1, NTH, 0, stream>>>(b10, b11, b20, b21, b30, b31, tab);

    const int grid = (N_NODES * 64) / NTH;   // 512 blocks (RPT=2)
    mace_main<<<grid, NTH, 0, stream>>>(
        nf, spec, tab, w10, w11, w20, w21, w30, w31, out);
}